// Round 1
// baseline (1796.516 us; speedup 1.0000x reference)
//
#include <hip/hip_runtime.h>
#include <math.h>

namespace {

constexpr int N_NODES = 200000;
constexpr int N_EDGES = 1000000;
constexpr int IN_D    = 64;
constexpr int ED      = 16;
constexpr int HD      = 128;
constexpr int NMOL    = 8000;
constexpr float EPS   = 1e-5f;
constexpr float SLOPE = 0.01f;

// ---------------------------------------------------------------------------
// Edge kernel: per edge e, compute e_vec = We @ edge_attr[e] + be,
// m = relu(x[src] + e_vec), atomicAdd into agg[dst].
// One wave per edge (grid-stride). Lane l owns output dim l (and l+64 if D=128).
// We rows live in per-lane registers (16 or 32 floats).
// ---------------------------------------------------------------------------
template <int D>
__global__ __launch_bounds__(256) void edge_kernel(
    const float* __restrict__ xin,      // [N, D]
    const int* __restrict__ srcp,       // [E]
    const int* __restrict__ dstp,       // [E]
    const float* __restrict__ ea,       // [E, 16]
    const float* __restrict__ We,       // [D, 16]
    const float* __restrict__ be,       // [D]
    float* __restrict__ agg)            // [N, D]
{
    const int lane = threadIdx.x & 63;
    const int wid  = (blockIdx.x * blockDim.x + threadIdx.x) >> 6;
    const int nw   = (gridDim.x * blockDim.x) >> 6;

    float w0[ED], w1[ED];
    const float b0 = be[lane];
    float b1 = 0.0f;
#pragma unroll
    for (int k = 0; k < ED; ++k) w0[k] = We[lane * ED + k];
    if (D == 128) {
        b1 = be[lane + 64];
#pragma unroll
        for (int k = 0; k < ED; ++k) w1[k] = We[(lane + 64) * ED + k];
    }

    for (int e = wid; e < N_EDGES; e += nw) {
        const int s = srcp[e];
        const int d = dstp[e];
        const float4 a0 = *reinterpret_cast<const float4*>(ea + (size_t)e * ED + 0);
        const float4 a1 = *reinterpret_cast<const float4*>(ea + (size_t)e * ED + 4);
        const float4 a2 = *reinterpret_cast<const float4*>(ea + (size_t)e * ED + 8);
        const float4 a3 = *reinterpret_cast<const float4*>(ea + (size_t)e * ED + 12);
        const float eav[ED] = {a0.x, a0.y, a0.z, a0.w, a1.x, a1.y, a1.z, a1.w,
                               a2.x, a2.y, a2.z, a2.w, a3.x, a3.y, a3.z, a3.w};

        float acc0 = b0;
#pragma unroll
        for (int k = 0; k < ED; ++k) acc0 = fmaf(w0[k], eav[k], acc0);
        float m0 = xin[(size_t)s * D + lane] + acc0;
        m0 = fmaxf(m0, 0.0f);
        atomicAdd(&agg[(size_t)d * D + lane], m0);

        if (D == 128) {
            float acc1 = b1;
#pragma unroll
            for (int k = 0; k < ED; ++k) acc1 = fmaf(w1[k], eav[k], acc1);
            float m1 = xin[(size_t)s * D + lane + 64] + acc1;
            m1 = fmaxf(m1, 0.0f);
            atomicAdd(&agg[(size_t)d * D + lane + 64], m1);
        }
    }
}

// ---------------------------------------------------------------------------
// Node kernel: h = leakyrelu(BN((x + agg) @ W^T + b)); writes h (layers 1,2)
// and accumulates partial[n] += dot(Wl_seg, h[n]). Layer 3 additionally
// scatter-adds dot(Wl_d, h3[n]) into poolmol[batch[n]] and skips h write.
// Block = 256 threads = 4 waves; block owns 16 nodes; wave owns 4 nodes;
// lane owns cols (lane, lane+64). W^T staged in LDS chunks (stride 129),
// a-tile staged in LDS (stride 33). In-place hout==agg is safe: all reads of
// this block's 16 rows finish (syncthreads) before the epilogue writes them.
// ---------------------------------------------------------------------------
template <int K, int LAYER>
__global__ __launch_bounds__(256) void node_kernel(
    const float* __restrict__ xin,    // [N, K]
    const float* __restrict__ agg,    // [N, K]
    const float* __restrict__ W,      // [128, K]
    const float* __restrict__ bias,   // [128]
    const float* __restrict__ gamma,
    const float* __restrict__ beta,
    const float* __restrict__ rmean,
    const float* __restrict__ rvar,
    const float* __restrict__ Wl,     // layer segment of final weight ([128], layer3: [256])
    const int* __restrict__ batch,    // [N] (layer 3 only)
    float* __restrict__ hout,         // [N, 128] (layers 1,2)
    float* __restrict__ partial,      // [N]
    float* __restrict__ poolmol)      // [NMOL] (layer 3 only)
{
    __shared__ float wt[32][HD + 1];   // transposed W chunk, pad to kill conflicts
    __shared__ float alds[16][33];     // a = x + agg tile

    const int t    = threadIdx.x;
    const int lane = t & 63;
    const int w    = t >> 6;
    const int n0   = blockIdx.x * 16;

    const int j0 = lane, j1 = lane + 64;
    const float sc0 = gamma[j0] * rsqrtf(rvar[j0] + EPS);
    const float sc1 = gamma[j1] * rsqrtf(rvar[j1] + EPS);
    const float sh0 = beta[j0] + (bias[j0] - rmean[j0]) * sc0;
    const float sh1 = beta[j1] + (bias[j1] - rmean[j1]) * sc1;
    const float wl0 = Wl[j0], wl1 = Wl[j1];
    float wld0 = 0.0f, wld1 = 0.0f;
    if (LAYER == 3) { wld0 = Wl[128 + j0]; wld1 = Wl[128 + j1]; }

    float acc[4][2] = {};

    for (int kc = 0; kc < K; kc += 32) {
        // stage W^T chunk: 32 x 128, coalesced global read, transposed LDS write
#pragma unroll
        for (int i = 0; i < (32 * HD) / 256; ++i) {
            const int idx = t + i * 256;
            const int kk = idx & 31, j = idx >> 5;
            wt[kk][j] = W[j * K + kc + kk];
        }
        // stage a-tile: 16 nodes x 32 k
#pragma unroll
        for (int i = 0; i < (16 * 32) / 256; ++i) {
            const int idx = t + i * 256;
            const int kk = idx & 31, nn = idx >> 5;
            const size_t g = (size_t)(n0 + nn) * K + kc + kk;
            alds[nn][kk] = xin[g] + agg[g];
        }
        __syncthreads();
#pragma unroll
        for (int k = 0; k < 32; ++k) {
            const float wa = wt[k][j0];
            const float wb = wt[k][j1];
#pragma unroll
            for (int i = 0; i < 4; ++i) {
                const float a = alds[w * 4 + i][k];
                acc[i][0] = fmaf(a, wa, acc[i][0]);
                acc[i][1] = fmaf(a, wb, acc[i][1]);
            }
        }
        __syncthreads();
    }

#pragma unroll
    for (int i = 0; i < 4; ++i) {
        const int node = n0 + w * 4 + i;
        float h0 = acc[i][0] * sc0 + sh0;
        float h1 = acc[i][1] * sc1 + sh1;
        h0 = h0 > 0.0f ? h0 : SLOPE * h0;
        h1 = h1 > 0.0f ? h1 : SLOPE * h1;
        if (LAYER < 3) {
            hout[(size_t)node * HD + j0] = h0;
            hout[(size_t)node * HD + j1] = h1;
        }
        float pc = h0 * wl0 + h1 * wl1;
#pragma unroll
        for (int off = 32; off > 0; off >>= 1) pc += __shfl_down(pc, off, 64);
        if (LAYER == 3) {
            float pd = h0 * wld0 + h1 * wld1;
#pragma unroll
            for (int off = 32; off > 0; off >>= 1) pd += __shfl_down(pd, off, 64);
            if (lane == 0) {
                partial[node] += pc;
                atomicAdd(&poolmol[batch[node]], pd);
            }
        } else if (LAYER == 1) {
            if (lane == 0) partial[node] = pc;
        } else {
            if (lane == 0) partial[node] += pc;
        }
    }
}

__global__ __launch_bounds__(256) void final_kernel(
    const float* __restrict__ partial,
    const float* __restrict__ poolmol,
    const int* __restrict__ batch,
    const float* __restrict__ bl,
    float* __restrict__ out)
{
    const int n = blockIdx.x * blockDim.x + threadIdx.x;
    if (n < N_NODES) {
        const float z = partial[n] + poolmol[batch[n]] + bl[0];
        out[n] = 1.0f / (1.0f + expf(-z));
    }
}

} // namespace

extern "C" void kernel_launch(void* const* d_in, const int* in_sizes, int n_in,
                              void* d_out, int out_size, void* d_ws, size_t ws_size,
                              hipStream_t stream)
{
    const float* x    = (const float*)d_in[0];
    const int*   ei   = (const int*)d_in[1];
    const float* ea   = (const float*)d_in[2];
    const int*   batch= (const int*)d_in[3];

    const float* We1 = (const float*)d_in[4];
    const float* be1 = (const float*)d_in[5];
    const float* W1  = (const float*)d_in[6];
    const float* b1  = (const float*)d_in[7];
    const float* g1  = (const float*)d_in[8];
    const float* bt1 = (const float*)d_in[9];
    const float* rm1 = (const float*)d_in[10];
    const float* rv1 = (const float*)d_in[11];

    const float* We2 = (const float*)d_in[12];
    const float* be2 = (const float*)d_in[13];
    const float* W2  = (const float*)d_in[14];
    const float* b2  = (const float*)d_in[15];
    const float* g2  = (const float*)d_in[16];
    const float* bt2 = (const float*)d_in[17];
    const float* rm2 = (const float*)d_in[18];
    const float* rv2 = (const float*)d_in[19];

    const float* We3 = (const float*)d_in[20];
    const float* be3 = (const float*)d_in[21];
    const float* W3  = (const float*)d_in[22];
    const float* b3  = (const float*)d_in[23];
    const float* g3  = (const float*)d_in[24];
    const float* bt3 = (const float*)d_in[25];
    const float* rm3 = (const float*)d_in[26];
    const float* rv3 = (const float*)d_in[27];

    const float* Wl  = (const float*)d_in[28];
    const float* bl  = (const float*)d_in[29];

    // workspace layout
    float* bufA    = (float*)d_ws;                       // [N,128]
    float* bufB    = bufA + (size_t)N_NODES * HD;        // [N,128]
    float* partial = bufB + (size_t)N_NODES * HD;        // [N]
    float* pool    = partial + N_NODES;                  // [NMOL]

    const int* srcp = ei;
    const int* dstp = ei + N_EDGES;

    const int EDGE_BLOCKS = 2048;
    const int NODE_BLOCKS = N_NODES / 16;  // 12500, exact

    // ---- layer 1 (K=64): agg64 lives in bufB, h1 -> bufA ----
    hipMemsetAsync(bufB, 0, (size_t)N_NODES * IN_D * sizeof(float), stream);
    hipMemsetAsync(pool, 0, (size_t)NMOL * sizeof(float), stream);
    edge_kernel<64><<<EDGE_BLOCKS, 256, 0, stream>>>(x, srcp, dstp, ea, We1, be1, bufB);
    node_kernel<64, 1><<<NODE_BLOCKS, 256, 0, stream>>>(
        x, bufB, W1, b1, g1, bt1, rm1, rv1, Wl + 0, nullptr, bufA, partial, nullptr);

    // ---- layer 2 (K=128): agg in bufB, h2 in-place in bufB ----
    hipMemsetAsync(bufB, 0, (size_t)N_NODES * HD * sizeof(float), stream);
    edge_kernel<128><<<EDGE_BLOCKS, 256, 0, stream>>>(bufA, srcp, dstp, ea, We2, be2, bufB);
    node_kernel<128, 2><<<NODE_BLOCKS, 256, 0, stream>>>(
        bufA, bufB, W2, b2, g2, bt2, rm2, rv2, Wl + 128, nullptr, bufB, partial, nullptr);

    // ---- layer 3 (K=128): agg in bufA (h1 dead), h3 never materialized ----
    hipMemsetAsync(bufA, 0, (size_t)N_NODES * HD * sizeof(float), stream);
    edge_kernel<128><<<EDGE_BLOCKS, 256, 0, stream>>>(bufB, srcp, dstp, ea, We3, be3, bufA);
    node_kernel<128, 3><<<NODE_BLOCKS, 256, 0, stream>>>(
        bufB, bufA, W3, b3, g3, bt3, rm3, rv3, Wl + 256, batch, nullptr, partial, pool);

    final_kernel<<<(N_NODES + 255) / 256, 256, 0, stream>>>(partial, pool, batch, bl, (float*)d_out);
}

// Round 2
// 1705.105 us; speedup vs baseline: 1.0536x; 1.0536x over previous
//
#include <hip/hip_runtime.h>
#include <math.h>

namespace {

constexpr int N_NODES = 200000;
constexpr int N_EDGES = 1000000;
constexpr int IN_D    = 64;
constexpr int ED      = 16;
constexpr int HD      = 128;
constexpr int NMOL    = 8000;
constexpr float EPS   = 1e-5f;
constexpr float SLOPE = 0.01f;

constexpr int SCAN_CH = 512;                                  // elems per scan chunk
constexpr int NCHUNK  = (N_NODES + SCAN_CH - 1) / SCAN_CH;    // 391

// ---------------------------------------------------------------------------
// CSR build: deg histogram -> chunk sums -> top scan -> chunk scan -> scatter
// ---------------------------------------------------------------------------
__global__ __launch_bounds__(256) void hist_kernel(const int* __restrict__ dstp,
                                                   int* __restrict__ deg)
{
    for (int e = blockIdx.x * blockDim.x + threadIdx.x; e < N_EDGES;
         e += gridDim.x * blockDim.x)
        atomicAdd(&deg[dstp[e]], 1);
}

__global__ __launch_bounds__(256) void chunk_sum_kernel(const int* __restrict__ deg,
                                                        int* __restrict__ csum)
{
    __shared__ int s[256];
    const int b = blockIdx.x, t = threadIdx.x;
    const int base = b * SCAN_CH;
    int v = 0;
    if (base + t < N_NODES) v += deg[base + t];
    if (base + t + 256 < N_NODES) v += deg[base + t + 256];
    s[t] = v;
    __syncthreads();
    for (int off = 128; off > 0; off >>= 1) {
        if (t < off) s[t] += s[t + off];
        __syncthreads();
    }
    if (t == 0) csum[b] = s[0];
}

__global__ __launch_bounds__(512) void scan_top_kernel(const int* __restrict__ csum,
                                                       int* __restrict__ coff,
                                                       int* __restrict__ rowstart)
{
    __shared__ int s[512];
    const int t = threadIdx.x;
    const int v = (t < NCHUNK) ? csum[t] : 0;
    s[t] = v;
    __syncthreads();
    for (int off = 1; off < 512; off <<= 1) {
        int x = (t >= off) ? s[t - off] : 0;
        __syncthreads();
        s[t] += x;
        __syncthreads();
    }
    if (t < NCHUNK) coff[t] = s[t] - v;   // exclusive
    if (t == 0) rowstart[N_NODES] = N_EDGES;
}

// writes rowstart[i] and cursor (reusing deg) = exclusive scan of deg
__global__ __launch_bounds__(512) void chunk_scan_kernel(int* __restrict__ deg,
                                                         const int* __restrict__ coff,
                                                         int* __restrict__ rowstart)
{
    __shared__ int s[512];
    const int b = blockIdx.x, t = threadIdx.x;
    const int i = b * SCAN_CH + t;
    const int v = (i < N_NODES) ? deg[i] : 0;
    s[t] = v;
    __syncthreads();
    for (int off = 1; off < 512; off <<= 1) {
        int x = (t >= off) ? s[t - off] : 0;
        __syncthreads();
        s[t] += x;
        __syncthreads();
    }
    if (i < N_NODES) {
        const int r = coff[b] + s[t] - v;
        rowstart[i] = r;
        deg[i] = r;   // deg now serves as the scatter cursor
    }
}

__global__ __launch_bounds__(256) void scatter_kernel(const int* __restrict__ dstp,
                                                      int* __restrict__ cursor,
                                                      int* __restrict__ perm)
{
    for (int e = blockIdx.x * blockDim.x + threadIdx.x; e < N_EDGES;
         e += gridDim.x * blockDim.x) {
        const int pos = atomicAdd(&cursor[dstp[e]], 1);
        perm[pos] = e;
    }
}

// ---------------------------------------------------------------------------
// Fused layer kernel. Block = 256 thr = 4 waves, owns 16 nodes.
// Phase A (gather): wave w computes a[node] = x[node] + sum_{e->node}
//   relu(x[src(e)] + We@ea[e] + be) for its 4 nodes, in registers (lane owns
//   dim lane and lane+64 when K==128), writes to LDS a-tile.
// Phase B (GEMM): h = leakyrelu(BN(a @ W^T + b)); layers 1,2 write h; all
//   layers accumulate partial[n] += dot(Wl_seg, h[n]); layer 3 adds
//   dot(Wl_pool, h3[n]) into poolmol[batch[n]] and writes no h.
// ---------------------------------------------------------------------------
template <int K, int LAYER>
__global__ __launch_bounds__(256) void layer_kernel(
    const float* __restrict__ xin,      // [N, K]
    const int* __restrict__ srcp,       // [E]
    const float* __restrict__ ea,       // [E, 16]
    const int* __restrict__ rowstart,   // [N+1]
    const int* __restrict__ perm,       // [E]
    const float* __restrict__ We,       // [K, 16]
    const float* __restrict__ be,       // [K]
    const float* __restrict__ W,        // [128, K]
    const float* __restrict__ bias,
    const float* __restrict__ gamma,
    const float* __restrict__ beta,
    const float* __restrict__ rmean,
    const float* __restrict__ rvar,
    const float* __restrict__ Wl,       // [128] (layer3: [256], second half = pool)
    const int* __restrict__ batch,      // layer 3 only
    float* __restrict__ hout,           // layers 1,2
    float* __restrict__ partial,        // [N]
    float* __restrict__ poolmol)        // layer 3 only
{
    __shared__ float wt[32][HD + 1];
    __shared__ float alds[16][K + 1];

    const int t    = threadIdx.x;
    const int lane = t & 63;
    const int w    = t >> 6;
    const int n0   = blockIdx.x * 16;

    // edge-linear rows for this lane's dims
    float w0[ED], w1[ED];
    const float b0 = be[lane];
    float b1 = 0.0f;
#pragma unroll
    for (int k = 0; k < ED; ++k) w0[k] = We[lane * ED + k];
    if (K == 128) {
        b1 = be[lane + 64];
#pragma unroll
        for (int k = 0; k < ED; ++k) w1[k] = We[(lane + 64) * ED + k];
    }

    // ---- Phase A: gather ----
#pragma unroll
    for (int i = 0; i < 4; ++i) {
        const int node = n0 + w * 4 + i;
        float acc0 = xin[(size_t)node * K + lane];
        float acc1 = (K == 128) ? xin[(size_t)node * K + lane + 64] : 0.0f;
        const int e0 = rowstart[node], e1 = rowstart[node + 1];
        int eid = (e0 < e1) ? perm[e0] : 0;
        for (int e = e0; e < e1; ++e) {
            const int s = srcp[eid];
            const float4 a0 = *reinterpret_cast<const float4*>(ea + (size_t)eid * ED + 0);
            const float4 a1 = *reinterpret_cast<const float4*>(ea + (size_t)eid * ED + 4);
            const float4 a2 = *reinterpret_cast<const float4*>(ea + (size_t)eid * ED + 8);
            const float4 a3 = *reinterpret_cast<const float4*>(ea + (size_t)eid * ED + 12);
            const int eid_next = (e + 1 < e1) ? perm[e + 1] : 0;  // prefetch
            const float eav[ED] = {a0.x, a0.y, a0.z, a0.w, a1.x, a1.y, a1.z, a1.w,
                                   a2.x, a2.y, a2.z, a2.w, a3.x, a3.y, a3.z, a3.w};
            float m0 = b0;
#pragma unroll
            for (int k = 0; k < ED; ++k) m0 = fmaf(w0[k], eav[k], m0);
            m0 += xin[(size_t)s * K + lane];
            acc0 += fmaxf(m0, 0.0f);
            if (K == 128) {
                float m1 = b1;
#pragma unroll
                for (int k = 0; k < ED; ++k) m1 = fmaf(w1[k], eav[k], m1);
                m1 += xin[(size_t)s * K + lane + 64];
                acc1 += fmaxf(m1, 0.0f);
            }
            eid = eid_next;
        }
        alds[w * 4 + i][lane] = acc0;
        if (K == 128) alds[w * 4 + i][lane + 64] = acc1;
    }
    __syncthreads();

    // ---- Phase B: node GEMM + BN + leakyrelu + final-linear partials ----
    const int j0 = lane, j1 = lane + 64;
    const float sc0 = gamma[j0] * rsqrtf(rvar[j0] + EPS);
    const float sc1 = gamma[j1] * rsqrtf(rvar[j1] + EPS);
    const float sh0 = beta[j0] + (bias[j0] - rmean[j0]) * sc0;
    const float sh1 = beta[j1] + (bias[j1] - rmean[j1]) * sc1;
    const float wl0 = Wl[j0], wl1 = Wl[j1];
    float wld0 = 0.0f, wld1 = 0.0f;
    if (LAYER == 3) { wld0 = Wl[128 + j0]; wld1 = Wl[128 + j1]; }

    float acc[4][2] = {};

    for (int kc = 0; kc < K; kc += 32) {
#pragma unroll
        for (int i = 0; i < (32 * HD) / 256; ++i) {
            const int idx = t + i * 256;
            const int kk = idx & 31, j = idx >> 5;
            wt[kk][j] = W[j * K + kc + kk];
        }
        __syncthreads();
#pragma unroll
        for (int k = 0; k < 32; ++k) {
            const float wa = wt[k][j0];
            const float wb = wt[k][j1];
#pragma unroll
            for (int i = 0; i < 4; ++i) {
                const float a = alds[w * 4 + i][kc + k];
                acc[i][0] = fmaf(a, wa, acc[i][0]);
                acc[i][1] = fmaf(a, wb, acc[i][1]);
            }
        }
        __syncthreads();
    }

#pragma unroll
    for (int i = 0; i < 4; ++i) {
        const int node = n0 + w * 4 + i;
        float h0 = acc[i][0] * sc0 + sh0;
        float h1 = acc[i][1] * sc1 + sh1;
        h0 = h0 > 0.0f ? h0 : SLOPE * h0;
        h1 = h1 > 0.0f ? h1 : SLOPE * h1;
        if (LAYER < 3) {
            hout[(size_t)node * HD + j0] = h0;
            hout[(size_t)node * HD + j1] = h1;
        }
        float pc = h0 * wl0 + h1 * wl1;
#pragma unroll
        for (int off = 32; off > 0; off >>= 1) pc += __shfl_down(pc, off, 64);
        if (LAYER == 3) {
            float pd = h0 * wld0 + h1 * wld1;
#pragma unroll
            for (int off = 32; off > 0; off >>= 1) pd += __shfl_down(pd, off, 64);
            if (lane == 0) {
                partial[node] += pc;
                atomicAdd(&poolmol[batch[node]], pd);
            }
        } else if (LAYER == 1) {
            if (lane == 0) partial[node] = pc;
        } else {
            if (lane == 0) partial[node] += pc;
        }
    }
}

__global__ __launch_bounds__(256) void final_kernel(
    const float* __restrict__ partial,
    const float* __restrict__ poolmol,
    const int* __restrict__ batch,
    const float* __restrict__ bl,
    float* __restrict__ out)
{
    const int n = blockIdx.x * blockDim.x + threadIdx.x;
    if (n < N_NODES) {
        const float z = partial[n] + poolmol[batch[n]] + bl[0];
        out[n] = 1.0f / (1.0f + expf(-z));
    }
}

} // namespace

extern "C" void kernel_launch(void* const* d_in, const int* in_sizes, int n_in,
                              void* d_out, int out_size, void* d_ws, size_t ws_size,
                              hipStream_t stream)
{
    const float* x     = (const float*)d_in[0];
    const int*   ei    = (const int*)d_in[1];
    const float* ea    = (const float*)d_in[2];
    const int*   batch = (const int*)d_in[3];

    const float* We1 = (const float*)d_in[4];
    const float* be1 = (const float*)d_in[5];
    const float* W1  = (const float*)d_in[6];
    const float* b1  = (const float*)d_in[7];
    const float* g1  = (const float*)d_in[8];
    const float* bt1 = (const float*)d_in[9];
    const float* rm1 = (const float*)d_in[10];
    const float* rv1 = (const float*)d_in[11];

    const float* We2 = (const float*)d_in[12];
    const float* be2 = (const float*)d_in[13];
    const float* W2  = (const float*)d_in[14];
    const float* b2  = (const float*)d_in[15];
    const float* g2  = (const float*)d_in[16];
    const float* bt2 = (const float*)d_in[17];
    const float* rm2 = (const float*)d_in[18];
    const float* rv2 = (const float*)d_in[19];

    const float* We3 = (const float*)d_in[20];
    const float* be3 = (const float*)d_in[21];
    const float* W3  = (const float*)d_in[22];
    const float* b3  = (const float*)d_in[23];
    const float* g3  = (const float*)d_in[24];
    const float* bt3 = (const float*)d_in[25];
    const float* rm3 = (const float*)d_in[26];
    const float* rv3 = (const float*)d_in[27];

    const float* Wl  = (const float*)d_in[28];
    const float* bl  = (const float*)d_in[29];

    const int* srcp = ei;
    const int* dstp = ei + N_EDGES;

    // workspace layout
    float* bufA     = (float*)d_ws;                      // [N,128] h1
    float* bufB     = bufA + (size_t)N_NODES * HD;       // [N,128] h2
    float* partial  = bufB + (size_t)N_NODES * HD;       // [N]
    float* pool     = partial + N_NODES;                 // [NMOL]
    int*   deg      = (int*)(pool + NMOL);               // [N] (then cursor)
    int*   rowstart = deg + N_NODES;                     // [N+1]
    int*   csum     = rowstart + N_NODES + 1;            // [NCHUNK]
    int*   coff     = csum + NCHUNK;                     // [NCHUNK]
    int*   perm     = coff + NCHUNK;                     // [E]

    // ---- CSR build (once per call; reused by all 3 layers) ----
    hipMemsetAsync(deg, 0, (size_t)N_NODES * sizeof(int), stream);
    hipMemsetAsync(pool, 0, (size_t)NMOL * sizeof(float), stream);
    hist_kernel<<<1024, 256, 0, stream>>>(dstp, deg);
    chunk_sum_kernel<<<NCHUNK, 256, 0, stream>>>(deg, csum);
    scan_top_kernel<<<1, 512, 0, stream>>>(csum, coff, rowstart);
    chunk_scan_kernel<<<NCHUNK, 512, 0, stream>>>(deg, coff, rowstart);
    scatter_kernel<<<1024, 256, 0, stream>>>(dstp, deg, perm);

    const int NODE_BLOCKS = N_NODES / 16;  // 12500

    // ---- layer 1 (K=64): h1 -> bufA ----
    layer_kernel<64, 1><<<NODE_BLOCKS, 256, 0, stream>>>(
        x, srcp, ea, rowstart, perm, We1, be1, W1, b1, g1, bt1, rm1, rv1,
        Wl + 0, nullptr, bufA, partial, nullptr);

    // ---- layer 2 (K=128): reads bufA, h2 -> bufB ----
    layer_kernel<128, 2><<<NODE_BLOCKS, 256, 0, stream>>>(
        bufA, srcp, ea, rowstart, perm, We2, be2, W2, b2, g2, bt2, rm2, rv2,
        Wl + 128, nullptr, bufB, partial, nullptr);

    // ---- layer 3 (K=128): reads bufB, h3 fused into partial/pool ----
    layer_kernel<128, 3><<<NODE_BLOCKS, 256, 0, stream>>>(
        bufB, srcp, ea, rowstart, perm, We3, be3, W3, b3, g3, bt3, rm3, rv3,
        Wl + 256, batch, nullptr, partial, pool);

    final_kernel<<<(N_NODES + 255) / 256, 256, 0, stream>>>(partial, pool, batch, bl, (float*)d_out);
}

// Round 4
// 1298.466 us; speedup vs baseline: 1.3836x; 1.3132x over previous
//
#include <hip/hip_runtime.h>
#include <math.h>

namespace {

constexpr int N_NODES = 200000;
constexpr int N_EDGES = 1000000;
constexpr int ED      = 16;
constexpr int HD      = 128;
constexpr int NMOL    = 8000;
constexpr float EPS   = 1e-5f;
constexpr float SLOPE = 0.01f;

constexpr int SCAN_CH = 512;
constexpr int NCHUNK  = (N_NODES + SCAN_CH - 1) / SCAN_CH;    // 391
constexpr int ECH     = 128;   // staged edges per block window (avg range = 80)

// ---------------------------------------------------------------------------
// CSR build: deg histogram -> chunk sums -> top scan -> chunk scan -> scatter
// ---------------------------------------------------------------------------
__global__ __launch_bounds__(256) void hist_kernel(const int* __restrict__ dstp,
                                                   int* __restrict__ deg)
{
    for (int e = blockIdx.x * blockDim.x + threadIdx.x; e < N_EDGES;
         e += gridDim.x * blockDim.x)
        atomicAdd(&deg[dstp[e]], 1);
}

__global__ __launch_bounds__(256) void chunk_sum_kernel(const int* __restrict__ deg,
                                                        int* __restrict__ csum)
{
    __shared__ int s[256];
    const int b = blockIdx.x, t = threadIdx.x;
    const int base = b * SCAN_CH;
    int v = 0;
    if (base + t < N_NODES) v += deg[base + t];
    if (base + t + 256 < N_NODES) v += deg[base + t + 256];
    s[t] = v;
    __syncthreads();
    for (int off = 128; off > 0; off >>= 1) {
        if (t < off) s[t] += s[t + off];
        __syncthreads();
    }
    if (t == 0) csum[b] = s[0];
}

__global__ __launch_bounds__(512) void scan_top_kernel(const int* __restrict__ csum,
                                                       int* __restrict__ coff,
                                                       int* __restrict__ rowstart)
{
    __shared__ int s[512];
    const int t = threadIdx.x;
    const int v = (t < NCHUNK) ? csum[t] : 0;
    s[t] = v;
    __syncthreads();
    for (int off = 1; off < 512; off <<= 1) {
        int x = (t >= off) ? s[t - off] : 0;
        __syncthreads();
        s[t] += x;
        __syncthreads();
    }
    if (t < NCHUNK) coff[t] = s[t] - v;   // exclusive
    if (t == 0) rowstart[N_NODES] = N_EDGES;
}

__global__ __launch_bounds__(512) void chunk_scan_kernel(int* __restrict__ deg,
                                                         const int* __restrict__ coff,
                                                         int* __restrict__ rowstart)
{
    __shared__ int s[512];
    const int b = blockIdx.x, t = threadIdx.x;
    const int i = b * SCAN_CH + t;
    const int v = (i < N_NODES) ? deg[i] : 0;
    s[t] = v;
    __syncthreads();
    for (int off = 1; off < 512; off <<= 1) {
        int x = (t >= off) ? s[t - off] : 0;
        __syncthreads();
        s[t] += x;
        __syncthreads();
    }
    if (i < N_NODES) {
        const int r = coff[b] + s[t] - v;
        rowstart[i] = r;
        deg[i] = r;   // becomes the scatter cursor
    }
}

__global__ __launch_bounds__(256) void scatter_kernel(const int* __restrict__ dstp,
                                                      int* __restrict__ cursor,
                                                      int* __restrict__ perm)
{
    for (int e = blockIdx.x * blockDim.x + threadIdx.x; e < N_EDGES;
         e += gridDim.x * blockDim.x) {
        const int pos = atomicAdd(&cursor[dstp[e]], 1);
        perm[pos] = e;
    }
}

// Materialize dst-sorted src ids (sequential writes). ea stays unpermuted;
// layer kernels gather its rows via perm into LDS (keeps workspace small).
__global__ __launch_bounds__(256) void permute_kernel(const int* __restrict__ perm,
                                                      const int* __restrict__ srcp,
                                                      int* __restrict__ srcs_perm)
{
    for (int pos = blockIdx.x * blockDim.x + threadIdx.x; pos < N_EDGES;
         pos += gridDim.x * blockDim.x)
        srcs_perm[pos] = srcp[perm[pos]];
}

// ---------------------------------------------------------------------------
// Fused layer kernel. Block = 256 thr = 4 waves, 16 nodes, contiguous edge
// range [rowstart[n0], rowstart[n0+16]).
// Phase A: per ECH window, stage src ids (coalesced) + ea rows (gathered via
// perm, 4 thr/edge) into LDS; then each wave walks its 4 nodes' edges in
// LOCKSTEP (wave-uniform predicates) with a depth-1 prefetch of the x-rows ->
// up to 8 outstanding 256B gathers per wave.
// Phase B: tiled node GEMM + BN + leakyrelu + final-linear partials.
// LDS: alds persists; gather region and W-tile region share a union.
// ---------------------------------------------------------------------------
template <int K, int LAYER>
__global__ __launch_bounds__(256, 4) void layer_kernel(
    const float* __restrict__ xin,       // [N, K]
    const float* __restrict__ ea,        // [E, 16] original order
    const int* __restrict__ perm,        // [E] dst-sorted edge ids
    const int* __restrict__ srcs_perm,   // [E] dst-sorted src ids
    const int* __restrict__ rowstart,    // [N+1]
    const float* __restrict__ We,        // [K, 16]
    const float* __restrict__ be,        // [K]
    const float* __restrict__ W,         // [128, K]
    const float* __restrict__ bias,
    const float* __restrict__ gamma,
    const float* __restrict__ beta,
    const float* __restrict__ rmean,
    const float* __restrict__ rvar,
    const float* __restrict__ Wl,        // [128] (layer3: [256], 2nd half = pool)
    const int* __restrict__ batch,       // layer 3 only
    float* __restrict__ hout,            // layers 1,2
    float* __restrict__ partial,         // [N]
    float* __restrict__ poolmol)         // layer 3 only
{
    __shared__ __align__(16) float alds[16][K + 4];
    // union region: phase A {s_ea, s_src, s_rs} / phase B {wt}
    __shared__ __align__(16) float u[2240];   // 8960B >= max(8772, 8256)
    float (*s_ea)[ED] = (float (*)[ED])u;                 // [ECH][16]
    int*   s_src      = (int*)(u + ECH * ED);             // [ECH]
    int*   s_rs       = (int*)(u + ECH * ED + ECH);       // [17]
    float (*wt)[HD + 1] = (float (*)[HD + 1])u;           // [16][129]

    const int t    = threadIdx.x;
    const int lane = t & 63;
    const int w    = t >> 6;
    const int n0   = blockIdx.x * 16;
    constexpr int KSH = (K == 128) ? 7 : 6;

    if (t < 17) s_rs[t] = rowstart[n0 + t];

    // stage x self-rows into alds (the "(1+eps)*x_i" term, eps=0)
#pragma unroll
    for (int i = 0; i < (16 * K) / 256; ++i) {
        const int idx = t + i * 256;
        const int nn = idx >> KSH, d = idx & (K - 1);
        alds[nn][d] = xin[(size_t)(n0 + nn) * K + d];
    }

    // edge-linear rows for this lane's dims, in registers
    float w0[ED], w1[ED];
    const float b0 = be[lane];
    float b1 = 0.0f;
#pragma unroll
    for (int k = 0; k < ED; ++k) w0[k] = We[lane * ED + k];
    if (K == 128) {
        b1 = be[lane + 64];
#pragma unroll
        for (int k = 0; k < ED; ++k) w1[k] = We[(lane + 64) * ED + k];
    }

    __syncthreads();   // self-rows + s_rs visible to all (needed even if 0 edges)

    const int rs_lo = s_rs[0];
    const int cnt   = s_rs[16] - rs_lo;

    float acc0[4] = {0.f, 0.f, 0.f, 0.f};
    float acc1[4] = {0.f, 0.f, 0.f, 0.f};

    for (int base = 0; base < cnt; base += ECH) {
        const int wcnt = min(cnt - base, ECH);
        const int gbase = rs_lo + base;
        // stage src ids (coalesced) + ea rows (gather via perm, 4 thr/edge)
        for (int i = t; i < wcnt; i += 256) s_src[i] = srcs_perm[gbase + i];
        for (int i = t; i < wcnt * 4; i += 256) {
            const int e = i >> 2, q = i & 3;
            const int eid = perm[gbase + e];     // 4x redundant read, L1-served
            ((float4*)&s_ea[e][0])[q] = ((const float4*)(ea + (size_t)eid * ED))[q];
        }
        __syncthreads();

        // wave-local clipped ranges for its 4 nodes
        int e0v[4], cntv[4];
        int maxc = 0;
#pragma unroll
        for (int i = 0; i < 4; ++i) {
            int a = s_rs[w * 4 + i] - gbase;     if (a < 0) a = 0;
            int b = s_rs[w * 4 + i + 1] - gbase; if (b > wcnt) b = wcnt;
            e0v[i] = a;
            cntv[i] = (b > a) ? (b - a) : 0;
            maxc = max(maxc, cntv[i]);
        }

        // depth-1 prefetch of first x-rows
        float pxa[4], pxb[4];
#pragma unroll
        for (int i = 0; i < 4; ++i) {
            pxa[i] = 0.f; pxb[i] = 0.f;
            if (cntv[i] > 0) {
                const int s = s_src[e0v[i]];
                pxa[i] = xin[(size_t)s * K + lane];
                if (K == 128) pxb[i] = xin[(size_t)s * K + lane + 64];
            }
        }

        for (int c = 0; c < maxc; ++c) {
            // issue next-edge loads for all 4 nodes first (overlap with compute)
            float nxa[4], nxb[4];
#pragma unroll
            for (int i = 0; i < 4; ++i) {
                nxa[i] = 0.f; nxb[i] = 0.f;
                if (c + 1 < cntv[i]) {
                    const int s = s_src[e0v[i] + c + 1];
                    nxa[i] = xin[(size_t)s * K + lane];
                    if (K == 128) nxb[i] = xin[(size_t)s * K + lane + 64];
                }
            }
            // compute with held values
#pragma unroll
            for (int i = 0; i < 4; ++i) {
                if (c < cntv[i]) {
                    const int e = e0v[i] + c;
                    float m0 = b0 + pxa[i];
                    float m1 = 0.f;
                    if (K == 128) m1 = b1 + pxb[i];
#pragma unroll
                    for (int q = 0; q < 4; ++q) {
                        const float4 ev = *((const float4*)&s_ea[e][q * 4]);
                        m0 = fmaf(w0[4 * q + 0], ev.x, m0);
                        m0 = fmaf(w0[4 * q + 1], ev.y, m0);
                        m0 = fmaf(w0[4 * q + 2], ev.z, m0);
                        m0 = fmaf(w0[4 * q + 3], ev.w, m0);
                        if (K == 128) {
                            m1 = fmaf(w1[4 * q + 0], ev.x, m1);
                            m1 = fmaf(w1[4 * q + 1], ev.y, m1);
                            m1 = fmaf(w1[4 * q + 2], ev.z, m1);
                            m1 = fmaf(w1[4 * q + 3], ev.w, m1);
                        }
                    }
                    acc0[i] += fmaxf(m0, 0.0f);
                    if (K == 128) acc1[i] += fmaxf(m1, 0.0f);
                }
                pxa[i] = nxa[i]; pxb[i] = nxb[i];
            }
        }
        __syncthreads();   // all waves done with s_ea/s_src before next stage
    }

    // fold register accumulators into the a-tile (wave-private rows)
#pragma unroll
    for (int i = 0; i < 4; ++i) {
        alds[w * 4 + i][lane] += acc0[i];
        if (K == 128) alds[w * 4 + i][lane + 64] += acc1[i];
    }

    // ---- Phase B: node GEMM + BN + leakyrelu + final-linear partials ----
    const int j0 = lane, j1 = lane + 64;
    const float sc0 = gamma[j0] * rsqrtf(rvar[j0] + EPS);
    const float sc1 = gamma[j1] * rsqrtf(rvar[j1] + EPS);
    const float sh0 = beta[j0] + (bias[j0] - rmean[j0]) * sc0;
    const float sh1 = beta[j1] + (bias[j1] - rmean[j1]) * sc1;
    const float wl0 = Wl[j0], wl1 = Wl[j1];
    float wld0 = 0.0f, wld1 = 0.0f;
    if (LAYER == 3) { wld0 = Wl[128 + j0]; wld1 = Wl[128 + j1]; }

    float acc[4][2] = {};

    for (int kc = 0; kc < K; kc += 16) {
        // stage W^T chunk (16 x 128): coalesced global, transposed LDS write.
        // First iteration overwrites the phase-A union region -- safe: last
        // window ended with __syncthreads().
#pragma unroll
        for (int i = 0; i < (16 * HD) / 256; ++i) {
            const int idx = t + i * 256;
            const int kk = idx & 15, j = idx >> 4;
            wt[kk][j] = W[j * K + kc + kk];
        }
        __syncthreads();
#pragma unroll
        for (int k4 = 0; k4 < 16; k4 += 4) {
            float4 av[4];
#pragma unroll
            for (int i = 0; i < 4; ++i)
                av[i] = *((const float4*)&alds[w * 4 + i][kc + k4]);
#pragma unroll
            for (int kk = 0; kk < 4; ++kk) {
                const float wa = wt[k4 + kk][j0];
                const float wb = wt[k4 + kk][j1];
#pragma unroll
                for (int i = 0; i < 4; ++i) {
                    const float a = ((const float*)&av[i])[kk];
                    acc[i][0] = fmaf(a, wa, acc[i][0]);
                    acc[i][1] = fmaf(a, wb, acc[i][1]);
                }
            }
        }
        __syncthreads();
    }

#pragma unroll
    for (int i = 0; i < 4; ++i) {
        const int node = n0 + w * 4 + i;
        float h0 = acc[i][0] * sc0 + sh0;
        float h1 = acc[i][1] * sc1 + sh1;
        h0 = h0 > 0.0f ? h0 : SLOPE * h0;
        h1 = h1 > 0.0f ? h1 : SLOPE * h1;
        if (LAYER < 3) {
            hout[(size_t)node * HD + j0] = h0;
            hout[(size_t)node * HD + j1] = h1;
        }
        float pc = h0 * wl0 + h1 * wl1;
#pragma unroll
        for (int off = 32; off > 0; off >>= 1) pc += __shfl_down(pc, off, 64);
        if (LAYER == 3) {
            float pd = h0 * wld0 + h1 * wld1;
#pragma unroll
            for (int off = 32; off > 0; off >>= 1) pd += __shfl_down(pd, off, 64);
            if (lane == 0) {
                partial[node] += pc;
                atomicAdd(&poolmol[batch[node]], pd);
            }
        } else if (LAYER == 1) {
            if (lane == 0) partial[node] = pc;
        } else {
            if (lane == 0) partial[node] += pc;
        }
    }
}

__global__ __launch_bounds__(256) void final_kernel(
    const float* __restrict__ partial,
    const float* __restrict__ poolmol,
    const int* __restrict__ batch,
    const float* __restrict__ bl,
    float* __restrict__ out)
{
    const int n = blockIdx.x * blockDim.x + threadIdx.x;
    if (n < N_NODES) {
        const float z = partial[n] + poolmol[batch[n]] + bl[0];
        out[n] = 1.0f / (1.0f + expf(-z));
    }
}

} // namespace

extern "C" void kernel_launch(void* const* d_in, const int* in_sizes, int n_in,
                              void* d_out, int out_size, void* d_ws, size_t ws_size,
                              hipStream_t stream)
{
    const float* x     = (const float*)d_in[0];
    const int*   ei    = (const int*)d_in[1];
    const float* ea    = (const float*)d_in[2];
    const int*   batch = (const int*)d_in[3];

    const float* We1 = (const float*)d_in[4];
    const float* be1 = (const float*)d_in[5];
    const float* W1  = (const float*)d_in[6];
    const float* b1  = (const float*)d_in[7];
    const float* g1  = (const float*)d_in[8];
    const float* bt1 = (const float*)d_in[9];
    const float* rm1 = (const float*)d_in[10];
    const float* rv1 = (const float*)d_in[11];

    const float* We2 = (const float*)d_in[12];
    const float* be2 = (const float*)d_in[13];
    const float* W2  = (const float*)d_in[14];
    const float* b2  = (const float*)d_in[15];
    const float* g2  = (const float*)d_in[16];
    const float* bt2 = (const float*)d_in[17];
    const float* rm2 = (const float*)d_in[18];
    const float* rv2 = (const float*)d_in[19];

    const float* We3 = (const float*)d_in[20];
    const float* be3 = (const float*)d_in[21];
    const float* W3  = (const float*)d_in[22];
    const float* b3  = (const float*)d_in[23];
    const float* g3  = (const float*)d_in[24];
    const float* bt3 = (const float*)d_in[25];
    const float* rm3 = (const float*)d_in[26];
    const float* rv3 = (const float*)d_in[27];

    const float* Wl  = (const float*)d_in[28];
    const float* bl  = (const float*)d_in[29];

    const int* srcp = ei;
    const int* dstp = ei + N_EDGES;

    // workspace carving (units of 4B elems, 16B-aligned slots)
    // total ~215 MB (round-2's 211 MB worked; round-3's 279 MB crashed)
    size_t off = 0;
    auto carve = [&](size_t elems) -> void* {
        void* p = (char*)d_ws + off * 4;
        off += (elems + 3) & ~(size_t)3;
        return p;
    };
    float* bufA      = (float*)carve((size_t)N_NODES * HD);   // h1
    float* bufB      = (float*)carve((size_t)N_NODES * HD);   // h2
    float* partial   = (float*)carve(N_NODES);
    float* pool      = (float*)carve(NMOL);
    int*   deg       = (int*)carve(N_NODES);                  // then cursor
    int*   rowstart  = (int*)carve(N_NODES + 1);
    int*   csum      = (int*)carve(NCHUNK);
    int*   coff      = (int*)carve(NCHUNK);
    int*   perm      = (int*)carve(N_EDGES);
    int*   srcs_perm = (int*)carve(N_EDGES);

    // ---- CSR build + src permute (once per call; reused by all 3 layers) ----
    hipMemsetAsync(deg, 0, (size_t)N_NODES * sizeof(int), stream);
    hipMemsetAsync(pool, 0, (size_t)NMOL * sizeof(float), stream);
    hist_kernel<<<1024, 256, 0, stream>>>(dstp, deg);
    chunk_sum_kernel<<<NCHUNK, 256, 0, stream>>>(deg, csum);
    scan_top_kernel<<<1, 512, 0, stream>>>(csum, coff, rowstart);
    chunk_scan_kernel<<<NCHUNK, 512, 0, stream>>>(deg, coff, rowstart);
    scatter_kernel<<<1024, 256, 0, stream>>>(dstp, deg, perm);
    permute_kernel<<<1024, 256, 0, stream>>>(perm, srcp, srcs_perm);

    const int NODE_BLOCKS = N_NODES / 16;  // 12500

    layer_kernel<64, 1><<<NODE_BLOCKS, 256, 0, stream>>>(
        x, ea, perm, srcs_perm, rowstart, We1, be1, W1, b1, g1, bt1, rm1, rv1,
        Wl + 0, nullptr, bufA, partial, nullptr);

    layer_kernel<128, 2><<<NODE_BLOCKS, 256, 0, stream>>>(
        bufA, ea, perm, srcs_perm, rowstart, We2, be2, W2, b2, g2, bt2, rm2, rv2,
        Wl + 128, nullptr, bufB, partial, nullptr);

    layer_kernel<128, 3><<<NODE_BLOCKS, 256, 0, stream>>>(
        bufB, ea, perm, srcs_perm, rowstart, We3, be3, W3, b3, g3, bt3, rm3, rv3,
        Wl + 256, batch, nullptr, partial, pool);

    final_kernel<<<(N_NODES + 255) / 256, 256, 0, stream>>>(partial, pool, batch, bl, (float*)d_out);
}

// Round 5
// 1031.321 us; speedup vs baseline: 1.7420x; 1.2590x over previous
//
#include <hip/hip_runtime.h>
#include <math.h>

namespace {

constexpr int N_NODES = 200000;
constexpr int N_EDGES = 1000000;
constexpr int ED      = 16;
constexpr int HD      = 128;
constexpr int NMOL    = 8000;
constexpr float EPS   = 1e-5f;
constexpr float SLOPE = 0.01f;

constexpr int SCAN_CH = 512;
constexpr int NCHUNK  = (N_NODES + SCAN_CH - 1) / SCAN_CH;    // 391
constexpr int ECH     = 128;   // staged edges per block window (avg range = 80)
constexpr int CH      = 8;     // gather pipeline chunk (edges per buffer)

// ---------------------------------------------------------------------------
// CSR build: deg histogram -> chunk sums -> top scan -> chunk scan -> scatter
// ---------------------------------------------------------------------------
__global__ __launch_bounds__(256) void hist_kernel(const int* __restrict__ dstp,
                                                   int* __restrict__ deg)
{
    for (int e = blockIdx.x * blockDim.x + threadIdx.x; e < N_EDGES;
         e += gridDim.x * blockDim.x)
        atomicAdd(&deg[dstp[e]], 1);
}

__global__ __launch_bounds__(256) void chunk_sum_kernel(const int* __restrict__ deg,
                                                        int* __restrict__ csum)
{
    __shared__ int s[256];
    const int b = blockIdx.x, t = threadIdx.x;
    const int base = b * SCAN_CH;
    int v = 0;
    if (base + t < N_NODES) v += deg[base + t];
    if (base + t + 256 < N_NODES) v += deg[base + t + 256];
    s[t] = v;
    __syncthreads();
    for (int off = 128; off > 0; off >>= 1) {
        if (t < off) s[t] += s[t + off];
        __syncthreads();
    }
    if (t == 0) csum[b] = s[0];
}

__global__ __launch_bounds__(512) void scan_top_kernel(const int* __restrict__ csum,
                                                       int* __restrict__ coff,
                                                       int* __restrict__ rowstart)
{
    __shared__ int s[512];
    const int t = threadIdx.x;
    const int v = (t < NCHUNK) ? csum[t] : 0;
    s[t] = v;
    __syncthreads();
    for (int off = 1; off < 512; off <<= 1) {
        int x = (t >= off) ? s[t - off] : 0;
        __syncthreads();
        s[t] += x;
        __syncthreads();
    }
    if (t < NCHUNK) coff[t] = s[t] - v;   // exclusive
    if (t == 0) rowstart[N_NODES] = N_EDGES;
}

__global__ __launch_bounds__(512) void chunk_scan_kernel(int* __restrict__ deg,
                                                         const int* __restrict__ coff,
                                                         int* __restrict__ rowstart)
{
    __shared__ int s[512];
    const int b = blockIdx.x, t = threadIdx.x;
    const int i = b * SCAN_CH + t;
    const int v = (i < N_NODES) ? deg[i] : 0;
    s[t] = v;
    __syncthreads();
    for (int off = 1; off < 512; off <<= 1) {
        int x = (t >= off) ? s[t - off] : 0;
        __syncthreads();
        s[t] += x;
        __syncthreads();
    }
    if (i < N_NODES) {
        const int r = coff[b] + s[t] - v;
        rowstart[i] = r;
        deg[i] = r;   // becomes the scatter cursor
    }
}

__global__ __launch_bounds__(256) void scatter_kernel(const int* __restrict__ dstp,
                                                      int* __restrict__ cursor,
                                                      int* __restrict__ perm)
{
    for (int e = blockIdx.x * blockDim.x + threadIdx.x; e < N_EDGES;
         e += gridDim.x * blockDim.x) {
        const int pos = atomicAdd(&cursor[dstp[e]], 1);
        perm[pos] = e;
    }
}

// Materialize dst-sorted src ids (sequential writes). ea stays unpermuted;
// layer kernels gather its rows via perm into LDS.
__global__ __launch_bounds__(256) void permute_kernel(const int* __restrict__ perm,
                                                      const int* __restrict__ srcp,
                                                      int* __restrict__ srcs_perm)
{
    for (int pos = blockIdx.x * blockDim.x + threadIdx.x; pos < N_EDGES;
         pos += gridDim.x * blockDim.x)
        srcs_perm[pos] = srcp[perm[pos]];
}

// ---------------------------------------------------------------------------
// Fused layer kernel. Block = 256 thr = 4 waves, 16 nodes, contiguous edge
// range [rowstart[n0], rowstart[n0+16]).
// Phase A: per ECH window, stage src ids + ea rows in LDS; each wave walks
// its 4 nodes' edges as ONE FLAT STREAM (dst-sorted => per-node runs) in
// chunks of CH=8, double-buffered: 16 x-row loads in flight while computing
// the previous 8 edges. Accumulates in 2 regs, flushes to the LDS a-tile at
// node boundaries (wave-uniform, <=4 per wave).
// Phase B: tiled node GEMM (32-row W chunks) + BN + leakyrelu + partials.
// ---------------------------------------------------------------------------
template <int K, int LAYER>
__global__ __launch_bounds__(256, 4) void layer_kernel(
    const float* __restrict__ xin,       // [N, K]
    const float* __restrict__ ea,        // [E, 16] original order
    const int* __restrict__ perm,        // [E] dst-sorted edge ids
    const int* __restrict__ srcs_perm,   // [E] dst-sorted src ids
    const int* __restrict__ rowstart,    // [N+1]
    const float* __restrict__ We,        // [K, 16]
    const float* __restrict__ be,        // [K]
    const float* __restrict__ W,         // [128, K]
    const float* __restrict__ bias,
    const float* __restrict__ gamma,
    const float* __restrict__ beta,
    const float* __restrict__ rmean,
    const float* __restrict__ rvar,
    const float* __restrict__ Wl,        // [128] (layer3: [256], 2nd half = pool)
    const int* __restrict__ batch,       // layer 3 only
    float* __restrict__ hout,            // layers 1,2
    float* __restrict__ partial,         // [N]
    float* __restrict__ poolmol)         // layer 3 only
{
    __shared__ __align__(16) float alds[16][K + 4];
    // union region: phase A {s_ea[128][16], s_src[128], s_rs[17]} (2193 w)
    //               phase B {wt[32][129]} (4128 w)
    __shared__ __align__(16) float u[4160];
    float (*s_ea)[ED] = (float (*)[ED])u;                 // [ECH][16]
    int*   s_src      = (int*)(u + ECH * ED);             // [ECH]
    int*   s_rs       = (int*)(u + ECH * ED + ECH);       // [17]
    float (*wt)[HD + 1] = (float (*)[HD + 1])u;           // [32][129]

    const int t    = threadIdx.x;
    const int lane = t & 63;
    const int w    = t >> 6;
    const int w4   = w * 4;
    const int n0   = blockIdx.x * 16;
    constexpr int KSH = (K == 128) ? 7 : 6;

    if (t < 17) s_rs[t] = rowstart[n0 + t];

    // stage x self-rows into alds (the "(1+eps)*x_i" term, eps=0)
#pragma unroll
    for (int i = 0; i < (16 * K) / 256; ++i) {
        const int idx = t + i * 256;
        const int nn = idx >> KSH, d = idx & (K - 1);
        alds[nn][d] = xin[(size_t)(n0 + nn) * K + d];
    }

    // edge-linear rows for this lane's dims, in registers
    float w0[ED], w1[ED];
    const float b0 = be[lane];
    float b1 = 0.0f;
#pragma unroll
    for (int k = 0; k < ED; ++k) w0[k] = We[lane * ED + k];
    if (K == 128) {
        b1 = be[lane + 64];
#pragma unroll
        for (int k = 0; k < ED; ++k) w1[k] = We[(lane + 64) * ED + k];
    }

    __syncthreads();   // self-rows + s_rs visible

    const int rs_lo      = s_rs[0];
    const int rs_hi_blk  = s_rs[16];
    const int flat_begin = s_rs[w4];
    const int flat_end4  = s_rs[w4 + 4];

    int   cur  = 0;                 // wave's current local node (0..3)
    int   bnd  = s_rs[w4 + 1];      // global edge index where node cur ends
    float acc0 = 0.f, acc1 = 0.f;   // running aggregate for node cur

    for (int gbase = rs_lo; gbase < rs_hi_blk; gbase += ECH) {
        const int wcnt = min(rs_hi_blk - gbase, ECH);
        // stage src ids (coalesced) + ea rows (gather via perm, 4 thr/edge)
        for (int i = t; i < wcnt; i += 256) s_src[i] = srcs_perm[gbase + i];
        for (int i = t; i < wcnt * 4; i += 256) {
            const int e = i >> 2, q = i & 3;
            const int eid = perm[gbase + e];
            ((float4*)&s_ea[e][0])[q] = ((const float4*)(ea + (size_t)eid * ED))[q];
        }
        __syncthreads();

        // this wave's flat sub-range within the window
        const int flat_lo = max(flat_begin, gbase);
        const int flat_hi = min(flat_end4, gbase + wcnt);
        const int nflat   = flat_hi - flat_lo;

        if (nflat > 0) {
            const int off = flat_lo - gbase;   // window-local index of 1st edge
            float A0[CH], A1[CH], B0[CH], B1[CH];
            // prologue: chunk 0
#pragma unroll
            for (int j = 0; j < CH; ++j) {
                const int l = off + min(j, nflat - 1);
                const int s = s_src[l];
                A0[j] = xin[(size_t)s * K + lane];
                if (K == 128) A1[j] = xin[(size_t)s * K + lane + 64];
            }
            for (int cb = 0; cb < nflat; cb += CH) {
                // issue next chunk's loads (16 in flight during compute)
#pragma unroll
                for (int j = 0; j < CH; ++j) {
                    const int l = off + min(cb + CH + j, nflat - 1);
                    const int s = s_src[l];
                    B0[j] = xin[(size_t)s * K + lane];
                    if (K == 128) B1[j] = xin[(size_t)s * K + lane + 64];
                }
                // compute current chunk
#pragma unroll
                for (int j = 0; j < CH; ++j) {
                    const int fe = cb + j;
                    if (fe < nflat) {                       // wave-uniform
                        const int ge = flat_lo + fe;        // global edge idx
                        while (ge >= bnd) {                 // node boundary
                            alds[w4 + cur][lane] += acc0;
                            if (K == 128) alds[w4 + cur][lane + 64] += acc1;
                            acc0 = 0.f; acc1 = 0.f;
                            ++cur;
                            bnd = s_rs[w4 + cur + 1];
                        }
                        const int l = off + fe;
                        float m0 = b0 + A0[j];
                        float m1 = 0.f;
                        if (K == 128) m1 = b1 + A1[j];
#pragma unroll
                        for (int q = 0; q < 4; ++q) {
                            const float4 ev = *((const float4*)&s_ea[l][q * 4]);
                            m0 = fmaf(w0[4 * q + 0], ev.x, m0);
                            m0 = fmaf(w0[4 * q + 1], ev.y, m0);
                            m0 = fmaf(w0[4 * q + 2], ev.z, m0);
                            m0 = fmaf(w0[4 * q + 3], ev.w, m0);
                            if (K == 128) {
                                m1 = fmaf(w1[4 * q + 0], ev.x, m1);
                                m1 = fmaf(w1[4 * q + 1], ev.y, m1);
                                m1 = fmaf(w1[4 * q + 2], ev.z, m1);
                                m1 = fmaf(w1[4 * q + 3], ev.w, m1);
                            }
                        }
                        acc0 += fmaxf(m0, 0.0f);
                        if (K == 128) acc1 += fmaxf(m1, 0.0f);
                    }
                    A0[j] = B0[j];
                    if (K == 128) A1[j] = B1[j];
                }
            }
        }
        __syncthreads();   // all waves done with s_ea/s_src before next stage
    }

    // final flush of the running accumulator (remaining nodes are self-only)
    alds[w4 + cur][lane] += acc0;
    if (K == 128) alds[w4 + cur][lane + 64] += acc1;
    __syncthreads();   // everyone done with s_rs before wt overwrites union

    // ---- Phase B: node GEMM + BN + leakyrelu + final-linear partials ----
    const int j0 = lane, j1 = lane + 64;
    const float sc0 = gamma[j0] * rsqrtf(rvar[j0] + EPS);
    const float sc1 = gamma[j1] * rsqrtf(rvar[j1] + EPS);
    const float sh0 = beta[j0] + (bias[j0] - rmean[j0]) * sc0;
    const float sh1 = beta[j1] + (bias[j1] - rmean[j1]) * sc1;
    const float wl0 = Wl[j0], wl1 = Wl[j1];
    float wld0 = 0.0f, wld1 = 0.0f;
    if (LAYER == 3) { wld0 = Wl[128 + j0]; wld1 = Wl[128 + j1]; }

    float acc[4][2] = {};

    for (int kc = 0; kc < K; kc += 32) {
        // stage W^T chunk (32 x 128): coalesced global, transposed LDS write
#pragma unroll
        for (int i = 0; i < (32 * HD) / 256; ++i) {
            const int idx = t + i * 256;
            const int kk = idx & 31, j = idx >> 5;
            wt[kk][j] = W[j * K + kc + kk];
        }
        __syncthreads();
#pragma unroll
        for (int k4 = 0; k4 < 32; k4 += 4) {
            float4 av[4];
#pragma unroll
            for (int i = 0; i < 4; ++i)
                av[i] = *((const float4*)&alds[w4 + i][kc + k4]);
#pragma unroll
            for (int kk = 0; kk < 4; ++kk) {
                const float wa = wt[k4 + kk][j0];
                const float wb = wt[k4 + kk][j1];
#pragma unroll
                for (int i = 0; i < 4; ++i) {
                    const float a = ((const float*)&av[i])[kk];
                    acc[i][0] = fmaf(a, wa, acc[i][0]);
                    acc[i][1] = fmaf(a, wb, acc[i][1]);
                }
            }
        }
        __syncthreads();
    }

#pragma unroll
    for (int i = 0; i < 4; ++i) {
        const int node = n0 + w4 + i;
        float h0 = acc[i][0] * sc0 + sh0;
        float h1 = acc[i][1] * sc1 + sh1;
        h0 = h0 > 0.0f ? h0 : SLOPE * h0;
        h1 = h1 > 0.0f ? h1 : SLOPE * h1;
        if (LAYER < 3) {
            hout[(size_t)node * HD + j0] = h0;
            hout[(size_t)node * HD + j1] = h1;
        }
        float pc = h0 * wl0 + h1 * wl1;
#pragma unroll
        for (int off = 32; off > 0; off >>= 1) pc += __shfl_down(pc, off, 64);
        if (LAYER == 3) {
            float pd = h0 * wld0 + h1 * wld1;
#pragma unroll
            for (int off = 32; off > 0; off >>= 1) pd += __shfl_down(pd, off, 64);
            if (lane == 0) {
                partial[node] += pc;
                atomicAdd(&poolmol[batch[node]], pd);
            }
        } else if (LAYER == 1) {
            if (lane == 0) partial[node] = pc;
        } else {
            if (lane == 0) partial[node] += pc;
        }
    }
}

__global__ __launch_bounds__(256) void final_kernel(
    const float* __restrict__ partial,
    const float* __restrict__ poolmol,
    const int* __restrict__ batch,
    const float* __restrict__ bl,
    float* __restrict__ out)
{
    const int n = blockIdx.x * blockDim.x + threadIdx.x;
    if (n < N_NODES) {
        const float z = partial[n] + poolmol[batch[n]] + bl[0];
        out[n] = 1.0f / (1.0f + expf(-z));
    }
}

} // namespace

extern "C" void kernel_launch(void* const* d_in, const int* in_sizes, int n_in,
                              void* d_out, int out_size, void* d_ws, size_t ws_size,
                              hipStream_t stream)
{
    const float* x     = (const float*)d_in[0];
    const int*   ei    = (const int*)d_in[1];
    const float* ea    = (const float*)d_in[2];
    const int*   batch = (const int*)d_in[3];

    const float* We1 = (const float*)d_in[4];
    const float* be1 = (const float*)d_in[5];
    const float* W1  = (const float*)d_in[6];
    const float* b1  = (const float*)d_in[7];
    const float* g1  = (const float*)d_in[8];
    const float* bt1 = (const float*)d_in[9];
    const float* rm1 = (const float*)d_in[10];
    const float* rv1 = (const float*)d_in[11];

    const float* We2 = (const float*)d_in[12];
    const float* be2 = (const float*)d_in[13];
    const float* W2  = (const float*)d_in[14];
    const float* b2  = (const float*)d_in[15];
    const float* g2  = (const float*)d_in[16];
    const float* bt2 = (const float*)d_in[17];
    const float* rm2 = (const float*)d_in[18];
    const float* rv2 = (const float*)d_in[19];

    const float* We3 = (const float*)d_in[20];
    const float* be3 = (const float*)d_in[21];
    const float* W3  = (const float*)d_in[22];
    const float* b3  = (const float*)d_in[23];
    const float* g3  = (const float*)d_in[24];
    const float* bt3 = (const float*)d_in[25];
    const float* rm3 = (const float*)d_in[26];
    const float* rv3 = (const float*)d_in[27];

    const float* Wl  = (const float*)d_in[28];
    const float* bl  = (const float*)d_in[29];

    const int* srcp = ei;
    const int* dstp = ei + N_EDGES;

    // workspace carving (units of 4B elems, 16B-aligned slots), ~215 MB
    size_t off = 0;
    auto carve = [&](size_t elems) -> void* {
        void* p = (char*)d_ws + off * 4;
        off += (elems + 3) & ~(size_t)3;
        return p;
    };
    float* bufA      = (float*)carve((size_t)N_NODES * HD);   // h1
    float* bufB      = (float*)carve((size_t)N_NODES * HD);   // h2
    float* partial   = (float*)carve(N_NODES);
    float* pool      = (float*)carve(NMOL);
    int*   deg       = (int*)carve(N_NODES);                  // then cursor
    int*   rowstart  = (int*)carve(N_NODES + 1);
    int*   csum      = (int*)carve(NCHUNK);
    int*   coff      = (int*)carve(NCHUNK);
    int*   perm      = (int*)carve(N_EDGES);
    int*   srcs_perm = (int*)carve(N_EDGES);

    // ---- CSR build + src permute (once per call; reused by all 3 layers) ----
    hipMemsetAsync(deg, 0, (size_t)N_NODES * sizeof(int), stream);
    hipMemsetAsync(pool, 0, (size_t)NMOL * sizeof(float), stream);
    hist_kernel<<<1024, 256, 0, stream>>>(dstp, deg);
    chunk_sum_kernel<<<NCHUNK, 256, 0, stream>>>(deg, csum);
    scan_top_kernel<<<1, 512, 0, stream>>>(csum, coff, rowstart);
    chunk_scan_kernel<<<NCHUNK, 512, 0, stream>>>(deg, coff, rowstart);
    scatter_kernel<<<1024, 256, 0, stream>>>(dstp, deg, perm);
    permute_kernel<<<1024, 256, 0, stream>>>(perm, srcp, srcs_perm);

    const int NODE_BLOCKS = N_NODES / 16;  // 12500

    layer_kernel<64, 1><<<NODE_BLOCKS, 256, 0, stream>>>(
        x, ea, perm, srcs_perm, rowstart, We1, be1, W1, b1, g1, bt1, rm1, rv1,
        Wl + 0, nullptr, bufA, partial, nullptr);

    layer_kernel<128, 2><<<NODE_BLOCKS, 256, 0, stream>>>(
        bufA, ea, perm, srcs_perm, rowstart, We2, be2, W2, b2, g2, bt2, rm2, rv2,
        Wl + 128, nullptr, bufB, partial, nullptr);

    layer_kernel<128, 3><<<NODE_BLOCKS, 256, 0, stream>>>(
        bufB, ea, perm, srcs_perm, rowstart, We3, be3, W3, b3, g3, bt3, rm3, rv3,
        Wl + 256, batch, nullptr, partial, pool);

    final_kernel<<<(N_NODES + 255) / 256, 256, 0, stream>>>(partial, pool, batch, bl, (float*)d_out);
}